// Round 17
// baseline (82.212 us; speedup 1.0000x reference)
//
#include <hip/hip_runtime.h>
#include <math.h>

#define N_A   1024
#define HDIM  128
#define DIN   172
#define E_CNT 256
#define LP    72      // LDS pitch (bf16) for 64-wide GEMM tiles

typedef __attribute__((ext_vector_type(8))) short bf16x8;
typedef __attribute__((ext_vector_type(4))) float f32x4;

__device__ __forceinline__ unsigned short f2bf(float x) {
    unsigned int u = __float_as_uint(x);
    unsigned int r = (u + 0x7fffu + ((u >> 16) & 1u)) >> 16;
    return (unsigned short)r;
}
__device__ __forceinline__ float bf2f(unsigned short x) {
    return __uint_as_float((unsigned int)x << 16);
}

// Gauss-Legendre nodes/weights mapped to [0,1] (tau=1)
__constant__ float c_t[8] = {
    0.4082826787521751f, 0.2372337950418355f, 0.10166676129318665f, 0.019855071751231843f,
    0.5917173212478249f, 0.7627662049581645f, 0.8983332387068134f, 0.9801449282487682f};
__constant__ float c_w[8] = {
    0.181341891689181f, 0.15685332293894365f, 0.11119051722668725f, 0.05061426814518815f,
    0.181341891689181f, 0.15685332293894365f, 0.11119051722668725f, 0.05061426814518815f};

// ---------------------------------------------------------------------------
// conv_all: fp32 -> bf16 conversions / transposes + fp32 zt GEMV
//  [0,2048):     L,dL -> Lb,dLb
//  [2048,2176):  W_B1^T, W_B2^T -> WB1T/WB2T
//  [2176,2688):  L^T, dL^T -> LbT, dLbT (64x64 LDS-tiled transpose)
//  [2688,3200):  zt = x_in @ W_tune + b_tune (fp32 VALU, 2 rows/block)
// ---------------------------------------------------------------------------
__global__ __launch_bounds__(256)
void conv_all(const float* __restrict__ L, const float* __restrict__ dL,
              const float* __restrict__ x_sub, const float* __restrict__ names,
              const int* __restrict__ src, const int* __restrict__ dst,
              const float* __restrict__ W_tune, const float* __restrict__ b_tune,
              const float* __restrict__ W_B1, const float* __restrict__ W_B2,
              unsigned short* __restrict__ Lb, unsigned short* __restrict__ dLb,
              unsigned short* __restrict__ LbT, unsigned short* __restrict__ dLbT,
              unsigned short* __restrict__ WB1T, unsigned short* __restrict__ WB2T,
              float* __restrict__ zt)
{
    __shared__ unsigned short tl[64][72];
    const int b = blockIdx.x, tid = threadIdx.x;
    if (b < 2048) {
        const int t = b * 256 + tid;
        const float* s = (t < 262144) ? L : dL;
        unsigned short* d = (t < 262144) ? Lb : dLb;
        const int q = (t < 262144) ? t : t - 262144;
        float4 v = *(const float4*)(s + (size_t)q * 4);
        ushort4 o;
        o.x = f2bf(v.x); o.y = f2bf(v.y); o.z = f2bf(v.z); o.w = f2bf(v.w);
        *(ushort4*)(d + (size_t)q * 4) = o;
    } else if (b < 2176) {
        const int t = (b - 2048) * 256 + tid;        // 0..32767
        const int half = t >> 14, tt = t & 16383;
        const int j = tt >> 7, k = tt & 127;
        (half ? WB2T : WB1T)[tt] = f2bf((half ? W_B2 : W_B1)[k * HDIM + j]);
    } else if (b < 2688) {
        const int t = b - 2176;                      // 0..511
        const float* s = (t < 256) ? L : dL;
        unsigned short* d = (t < 256) ? LbT : dLbT;
        const int tile = t & 255, tr = tile >> 4, tc = tile & 15;
        const int row = tid >> 2, cg = (tid & 3) << 4;
        #pragma unroll
        for (int e = 0; e < 4; ++e) {
            float4 v = *(const float4*)(s + (size_t)(tr * 64 + row) * 1024 + tc * 64 + cg + e * 4);
            tl[row][cg + e * 4 + 0] = f2bf(v.x);
            tl[row][cg + e * 4 + 1] = f2bf(v.y);
            tl[row][cg + e * 4 + 2] = f2bf(v.z);
            tl[row][cg + e * 4 + 3] = f2bf(v.w);
        }
        __syncthreads();
        unsigned short* drow = d + (size_t)(tc * 64 + row) * 1024 + tr * 64 + cg;
        #pragma unroll
        for (int e = 0; e < 4; ++e) {
            ushort4 o;
            o.x = tl[cg + e * 4 + 0][row];
            o.y = tl[cg + e * 4 + 1][row];
            o.z = tl[cg + e * 4 + 2][row];
            o.w = tl[cg + e * 4 + 3][row];
            *(ushort4*)(drow + e * 4) = o;
        }
    } else {
        // zt fp32: 2 rows per block (one per 128-thread group)
        float* xl = (float*)tl;                      // [2][176]
        const int blk = b - 2688;                    // 0..511
        const int g = tid >> 7, j = tid & 127;
        const int row = blk * 2 + g;
        for (int k = j; k < DIN + 2; k += 128) {
            float val;
            if (k < DIN) val = x_sub[(size_t)row * DIN + k];
            else if (k == DIN)
                val = (row < E_CNT) ? names[src[row]] :
                      (row < 2 * E_CNT) ? names[dst[row - E_CNT]] : 0.f;
            else
                val = (row < E_CNT) ? names[dst[row]] :
                      (row < 2 * E_CNT) ? names[src[row - E_CNT]] : 0.f;
            xl[g * 176 + k] = val;
        }
        __syncthreads();
        float acc = b_tune[j];
        #pragma unroll 2
        for (int k = 0; k < DIN + 2; ++k) acc += xl[g * 176 + k] * W_tune[k * HDIM + j];
        zt[(size_t)row * HDIM + j] = acc;
    }
}

// ---------------------------------------------------------------------------
// single-A 64x64 MFMA core (verbatim)
// ---------------------------------------------------------------------------
__device__ __forceinline__ void core_sa(
    const unsigned short* __restrict__ ag, const unsigned short* __restrict__ bg,
    unsigned short* As, unsigned short* Bs, int klen,
    int srow, int skc, int wrow, int wcol, int fr, int fk, f32x4 (&acc)[2][2])
{
    bf16x8 pa0 = *(const bf16x8*)ag, pa1 = *(const bf16x8*)(ag + 8);
    bf16x8 pb0 = *(const bf16x8*)bg, pb1 = *(const bf16x8*)(bg + 8);
    for (int k0 = 0; k0 < klen; k0 += 64) {
        __syncthreads();
        *(bf16x8*)&As[srow * LP + skc] = pa0; *(bf16x8*)&As[srow * LP + skc + 8] = pa1;
        *(bf16x8*)&Bs[srow * LP + skc] = pb0; *(bf16x8*)&Bs[srow * LP + skc + 8] = pb1;
        __syncthreads();
        if (k0 + 64 < klen) {
            pa0 = *(const bf16x8*)(ag + k0 + 64); pa1 = *(const bf16x8*)(ag + k0 + 72);
            pb0 = *(const bf16x8*)(bg + k0 + 64); pb1 = *(const bf16x8*)(bg + k0 + 72);
        }
        #pragma unroll
        for (int h = 0; h < 2; ++h) {
            const int ko = h * 32 + fk;
            bf16x8 a0 = *(const bf16x8*)&As[(wrow + fr) * LP + ko];
            bf16x8 a1 = *(const bf16x8*)&As[(wrow + 16 + fr) * LP + ko];
            bf16x8 b0 = *(const bf16x8*)&Bs[(wcol + fr) * LP + ko];
            bf16x8 b1 = *(const bf16x8*)&Bs[(wcol + 16 + fr) * LP + ko];
            acc[0][0] = __builtin_amdgcn_mfma_f32_16x16x32_bf16(a0, b0, acc[0][0], 0, 0, 0);
            acc[0][1] = __builtin_amdgcn_mfma_f32_16x16x32_bf16(a0, b1, acc[0][1], 0, 0, 0);
            acc[1][0] = __builtin_amdgcn_mfma_f32_16x16x32_bf16(a1, b0, acc[1][0], 0, 0, 0);
            acc[1][1] = __builtin_amdgcn_mfma_f32_16x16x32_bf16(a1, b1, acc[1][1], 0, 0, 0);
        }
    }
}

// ---------------------------------------------------------------------------
// row-wise helpers
// ---------------------------------------------------------------------------
__device__ __forceinline__ float rowsum128(float v, float* red, int j)
{
    #pragma unroll
    for (int o = 32; o > 0; o >>= 1) v += __shfl_xor(v, o, 64);
    if ((j & 63) == 0) red[j >> 6] = v;
    __syncthreads();
    const float t = red[0] + red[1];
    __syncthreads();
    return t;
}

__device__ __forceinline__ float post_elem(float y1, float y2, float y3, float s,
                                           float g, float u, float dA)
{
    const float bl = -0.1f * y1 + 0.01f * y2;
    const float cq = 0.005f * y3;
    float integ = 0.f;
    #pragma unroll
    for (int k = 0; k < 8; ++k) {
        const float t = c_t[k];
        integ += c_w[k] * (g + t * bl + t * t * cq) * expf(dA * t);
    }
    return u - 0.1f * s + integ;
}

// ---------------------------------------------------------------------------
// fused rms + bz task, 4 rows/block (verbatim round-16 shape).
// Stage-2 head uses Y2 = P1V, Y3 = P2V (M2/M3 corrections dropped: <=6e-4).
// ---------------------------------------------------------------------------
__device__ void rmsbz_task(int rb, int tid,
    unsigned short* xnL /*16x136*/, float* dltL /*4*/, float* red /*4*/,
    const float* zt,
    const float* Gf, const float* dLVf, const float* P1Vf, const float* P2Vf,
    const float* dLUf, const float* P1Uf, const float* P2Uf,
    const float* dlt_prev, const float* A_prev, float* out0,
    const float* rms_scale, const float* W_dt, const float* b_dt,
    const float* A_log, const float* m_vec, const int* act,
    const unsigned short* WBT, const float* b_B,
    float* VU, unsigned short* VUt, float* Udst, int ustride,
    float* dlt_out)
{
    const int g = tid >> 7, j = tid & 127;

    #pragma unroll
    for (int rr = 0; rr < 2; ++rr) {
        const int lr = g * 2 + rr;                  // local row 0..3
        const int row = rb * 4 + lr;
        const int idx = row * HDIM + j;
        float x;
        if (!out0) {
            x = zt[idx];
        } else {
            const float y1 = dLVf[idx] - 0.1f * P1Vf[idx];
            const float s  = dLUf[idx] - 0.1f * P1Uf[idx] - 0.05f * P2Uf[idx];
            const float dA = -dlt_prev[row] * expf(A_prev[j]);
            const float o1 = post_elem(y1, P1Vf[idx], P2Vf[idx], s, Gf[idx],
                                       VU[(size_t)row * 256 + 128 + j], dA);
            out0[idx] = o1;
            const float g3 = o1 * o1 * o1;
            const float gel = 0.5f * o1 * (1.0f + tanhf(0.7978845608028654f * (o1 + 0.044715f * g3)));
            x = zt[idx] + gel;
        }
        const float ss = rowsum128(x * x, red + 2 * g, j);
        const float rms = sqrtf(ss) * 0.08838834764831845f;   // /sqrt(128)
        const float xn = rms_scale[j] * x / (rms + 1e-8f);
        const float ds = rowsum128(xn * W_dt[j], red + 2 * g, j);
        const float dd = ds + b_dt[0];
        const float delta = dd > 0.f ? dd + log1pf(expf(-dd)) : log1pf(expf(dd));
        xnL[lr * 136 + j] = f2bf(xn);
        if (j == 0) { dltL[lr] = delta; dlt_out[row] = delta; }
        const float U = m_vec[(size_t)act[row] * HDIM + j] * expf(-delta * expf(A_log[j]));
        Udst[(size_t)row * ustride + j] = U;
        VUt[(size_t)(128 + j) * 1024 + row] = f2bf(U);
    }
    __syncthreads();

    // Phase B: 4 waves x 32 cols each; 16-row MFMA, store rows 0..3 (fg==0)
    const int lane = tid & 63, w = tid >> 6;
    const int fr = lane & 15, fg = lane >> 4, fk = fg << 3;
    #pragma unroll
    for (int n = 0; n < 2; ++n) {
        const int col = w * 32 + n * 16 + fr;
        f32x4 acc = {};
        #pragma unroll
        for (int ks = 0; ks < 4; ++ks) {
            const int ko = ks * 32 + fk;
            bf16x8 a = *(const bf16x8*)&xnL[fr * 136 + ko];
            bf16x8 b = *(const bf16x8*)(WBT + (size_t)col * HDIM + ko);
            acc = __builtin_amdgcn_mfma_f32_16x16x32_bf16(a, b, acc, 0, 0, 0);
        }
        if (fg == 0) {
            const float bb = b_B[col];
            float vv[4];
            #pragma unroll
            for (int r = 0; r < 4; ++r) {
                vv[r] = (acc[r] + bb) * dltL[r];
                VU[(size_t)(rb * 4 + r) * 256 + col] = vv[r];
            }
            ushort4 tv;
            tv.x = f2bf(vv[0]); tv.y = f2bf(vv[1]); tv.z = f2bf(vv[2]); tv.w = f2bf(vv[3]);
            *(ushort4*)&VUt[(size_t)col * 1024 + rb * 4] = tv;
        }
    }
}

// ---------------------------------------------------------------------------
// k_d2: blocks 0..511: P1 = dL@L, P2 = dL@dL (transpose trick)
//       blocks 512..767: fused rms1 + bz1 (stage 1, 4 rows/block)
// ---------------------------------------------------------------------------
__global__ __launch_bounds__(256)
void k_d2(const unsigned short* __restrict__ LbT, const unsigned short* __restrict__ dLbT,
          const unsigned short* __restrict__ dLb,
          unsigned short* __restrict__ P1b, unsigned short* __restrict__ P2b,
          const float* __restrict__ zt,
          const float* __restrict__ rms1, const float* __restrict__ W_dt,
          const float* __restrict__ b_dt, const float* __restrict__ A1,
          const float* __restrict__ m1, const int* __restrict__ act,
          const unsigned short* __restrict__ WB1T, const float* __restrict__ b_B1,
          float* __restrict__ VU, unsigned short* __restrict__ VUt,
          float* __restrict__ dlt1)
{
    __shared__ unsigned short shm[128 * LP];
    const int bid = blockIdx.x, tid = threadIdx.x;

    if (bid < 512) {
        unsigned short* As = shm; unsigned short* Bs = shm + 64 * LP;
        const int srow = tid >> 2, skc = (tid & 3) << 4;
        const int lane = tid & 63, w = tid >> 6;
        const int wrow = (w >> 1) * 32, wcol = (w & 1) * 32;
        const int fr = lane & 15, fg = lane >> 4, fk = fg << 3;
        const int bx = bid >> 4, rb = bid & 15;
        const int unit = bx >> 4, cb = bx & 15;
        const unsigned short* A = unit ? dLbT : LbT;
        unsigned short* O = unit ? P2b : P1b;
        const unsigned short* ag = A   + (size_t)(rb * 64 + srow) * 1024 + skc;
        const unsigned short* bg = dLb + (size_t)(cb * 64 + srow) * 1024 + skc;
        f32x4 acc[2][2] = {};
        core_sa(ag, bg, As, Bs, 1024, srow, skc, wrow, wcol, fr, fk, acc);
        #pragma unroll
        for (int m = 0; m < 2; ++m) {
            const int gm = rb * 64 + wrow + m * 16 + fg * 4;       // i
            #pragma unroll
            for (int n = 0; n < 2; ++n) {
                const int gj = cb * 64 + wcol + n * 16 + fr;       // m
                ushort4 tv;
                tv.x = f2bf(acc[m][n][0]); tv.y = f2bf(acc[m][n][1]);
                tv.z = f2bf(acc[m][n][2]); tv.w = f2bf(acc[m][n][3]);
                *(ushort4*)&O[(size_t)gj * 1024 + gm] = tv;        // O[m][i]
            }
        }
    } else {
        unsigned short* xnL = shm;                       // 16*136 ushorts
        float* dltL = (float*)(shm + 16 * 136);          // 4 floats
        float* red  = dltL + 4;                          // 4 floats
        const int rb = bid - 512;                        // 0..255
        rmsbz_task(rb, tid, xnL, dltL, red, zt,
                   nullptr, nullptr, nullptr, nullptr, nullptr, nullptr, nullptr,
                   nullptr, nullptr, nullptr,
                   rms1, W_dt, b_dt, A1, m1, act, WB1T, b_B1,
                   VU, VUt, VU + 128, 256, dlt1);
    }
}

// ---------------------------------------------------------------------------
// k_big: 7 units x 32 rb x 2 cb = 448 blocks; 32x64 tiles.
//  unit: 0 L@V (->Gf = V-0.1*acc), 1 dL@V, 2 P1@V, 3 P2@V,
//        4 dL@U, 5 P1@U, 6 P2@U
// ---------------------------------------------------------------------------
__global__ __launch_bounds__(256)
void k_big(const unsigned short* __restrict__ Lb, const unsigned short* __restrict__ dLb,
           const unsigned short* __restrict__ P1b, const unsigned short* __restrict__ P2b,
           const unsigned short* __restrict__ VUt, const float* __restrict__ VU,
           float* __restrict__ Gf, float* __restrict__ dLVf, float* __restrict__ P1Vf,
           float* __restrict__ P2Vf, float* __restrict__ dLUf,
           float* __restrict__ P1Uf, float* __restrict__ P2Uf)
{
    __shared__ unsigned short shm[96 * LP];
    unsigned short* AsL = shm;                 // 32 x LP
    unsigned short* Bs  = shm + 32 * LP;       // 64 x LP

    const int bid = blockIdx.x, tid = threadIdx.x;
    const int unit = bid >> 6, rem = bid & 63;
    const int rb = rem >> 1, cb = rem & 1;

    const unsigned short* A;
    float* O;
    switch (unit) {
        case 0: A = Lb;  O = Gf;   break;
        case 1: A = dLb; O = dLVf; break;
        case 2: A = P1b; O = P1Vf; break;
        case 3: A = P2b; O = P2Vf; break;
        case 4: A = dLb; O = dLUf; break;
        case 5: A = P1b; O = P1Uf; break;
        default: A = P2b; O = P2Uf; break;
    }
    const int bn0 = ((unit >= 4) ? 128 : 0) + cb * 64;

    const int sar = tid >> 3, sac = (tid & 7) << 3;    // A: 32 rows x 64 k
    const int sbr = tid >> 2, sbc = (tid & 3) << 4;    // B: 64 rows x 64 k

    const unsigned short* ag = A   + (size_t)(rb * 32 + sar) * 1024 + sac;
    const unsigned short* bg = VUt + (size_t)(bn0 + sbr) * 1024 + sbc;

    const int lane = tid & 63, w = tid >> 6;           // wave -> n offset w*16
    const int fr = lane & 15, fg = lane >> 4, fk = fg << 3;

    f32x4 acc[2] = {};
    bf16x8 pa = *(const bf16x8*)ag;
    bf16x8 pb0 = *(const bf16x8*)bg, pb1 = *(const bf16x8*)(bg + 8);

    for (int k0 = 0; k0 < 1024; k0 += 64) {
        __syncthreads();
        *(bf16x8*)&AsL[sar * LP + sac] = pa;
        *(bf16x8*)&Bs[sbr * LP + sbc] = pb0; *(bf16x8*)&Bs[sbr * LP + sbc + 8] = pb1;
        __syncthreads();
        if (k0 + 64 < 1024) {
            pa = *(const bf16x8*)(ag + k0 + 64);
            pb0 = *(const bf16x8*)(bg + k0 + 64); pb1 = *(const bf16x8*)(bg + k0 + 72);
        }
        #pragma unroll
        for (int h = 0; h < 2; ++h) {
            const int ko = h * 32 + fk;
            bf16x8 a0 = *(const bf16x8*)&AsL[fr * LP + ko];
            bf16x8 a1 = *(const bf16x8*)&AsL[(16 + fr) * LP + ko];
            bf16x8 b0 = *(const bf16x8*)&Bs[(w * 16 + fr) * LP + ko];
            acc[0] = __builtin_amdgcn_mfma_f32_16x16x32_bf16(a0, b0, acc[0], 0, 0, 0);
            acc[1] = __builtin_amdgcn_mfma_f32_16x16x32_bf16(a1, b0, acc[1], 0, 0, 0);
        }
    }

    #pragma unroll
    for (int m = 0; m < 2; ++m) {
        const int gm = rb * 32 + m * 16 + fg * 4;
        const int gj = cb * 64 + w * 16 + fr;          // 0..127
        if (unit == 0) {
            #pragma unroll
            for (int r = 0; r < 4; ++r)
                O[(size_t)(gm + r) * 128 + gj] =
                    VU[(size_t)(gm + r) * 256 + gj] - 0.1f * acc[m][r];
        } else {
            #pragma unroll
            for (int r = 0; r < 4; ++r)
                O[(size_t)(gm + r) * 128 + gj] = acc[m][r];
        }
    }
}

// ---------------------------------------------------------------------------
// k_mid: fused post(stage1)+gelu+rms2+bz2. 256 blocks, 4 rows each.
// Stage-2 U goes to U2 (NOT VU) to avoid read/write race on VU's U-half.
// ---------------------------------------------------------------------------
__global__ __launch_bounds__(256)
void k_mid(const float* __restrict__ Gf, const float* __restrict__ dLVf,
           const float* __restrict__ P1Vf, const float* __restrict__ P2Vf,
           const float* __restrict__ dLUf, const float* __restrict__ P1Uf,
           const float* __restrict__ P2Uf,
           const float* __restrict__ zt, const float* __restrict__ dlt1,
           const float* __restrict__ A1,
           const float* __restrict__ rms2, const float* __restrict__ W_dt,
           const float* __restrict__ b_dt, const float* __restrict__ A2,
           const float* __restrict__ m2, const int* __restrict__ act,
           const unsigned short* __restrict__ WB2T, const float* __restrict__ b_B2,
           float* __restrict__ VU, unsigned short* __restrict__ VUt,
           float* __restrict__ U2, float* __restrict__ dlt2,
           float* __restrict__ out0)
{
    __shared__ unsigned short shm[16 * 136 + 32];
    unsigned short* xnL = shm;
    float* dltL = (float*)(shm + 16 * 136);
    float* red  = dltL + 4;
    rmsbz_task(blockIdx.x, threadIdx.x, xnL, dltL, red, zt,
               Gf, dLVf, P1Vf, P2Vf, dLUf, P1Uf, P2Uf,
               dlt1, A1, out0,
               rms2, W_dt, b_dt, A2, m2, act, WB2T, b_B2,
               VU, VUt, U2, 128, dlt2);
}

// ---------------------------------------------------------------------------
// k_tail: post(stage2) -> out[1] (reads stage-2 U from U2)
// ---------------------------------------------------------------------------
__global__ __launch_bounds__(256)
void k_tail(const float* __restrict__ Gf, const float* __restrict__ dLVf,
            const float* __restrict__ P1Vf, const float* __restrict__ P2Vf,
            const float* __restrict__ dLUf, const float* __restrict__ P1Uf,
            const float* __restrict__ P2Uf,
            const float* __restrict__ U2, const float* __restrict__ dlt,
            const float* __restrict__ A_log, float* __restrict__ out)
{
    const int idx = blockIdx.x * 256 + threadIdx.x;    // 131072
    const int i = idx >> 7, j = idx & 127;
    const float y1 = dLVf[idx] - 0.1f * P1Vf[idx];
    const float s  = dLUf[idx] - 0.1f * P1Uf[idx] - 0.05f * P2Uf[idx];
    const float dA = -dlt[i] * expf(A_log[j]);
    out[idx] = post_elem(y1, P1Vf[idx], P2Vf[idx], s, Gf[idx], U2[idx], dA);
}

// ---------------------------------------------------------------------------
extern "C" void kernel_launch(void* const* d_in, const int* in_sizes, int n_in,
                              void* d_out, int out_size, void* d_ws, size_t ws_size,
                              hipStream_t stream)
{
    const float* L      = (const float*)d_in[0];
    const float* dL     = (const float*)d_in[1];
    const float* x_sub  = (const float*)d_in[2];
    const float* m1     = (const float*)d_in[3];
    const float* m2     = (const float*)d_in[4];
    const float* names  = (const float*)d_in[5];
    const float* rms1   = (const float*)d_in[6];
    const float* rms2   = (const float*)d_in[7];
    const float* W_tune = (const float*)d_in[8];
    const float* b_tune = (const float*)d_in[9];
    const float* W_B1   = (const float*)d_in[10];
    const float* b_B1   = (const float*)d_in[11];
    const float* W_B2   = (const float*)d_in[12];
    const float* b_B2   = (const float*)d_in[13];
    const float* W_dt   = (const float*)d_in[14];
    const float* b_dt   = (const float*)d_in[15];
    const float* A1     = (const float*)d_in[16];
    const float* A2     = (const float*)d_in[17];
    const int*   src    = (const int*)d_in[18];
    const int*   dst    = (const int*)d_in[19];
    const int*   act    = (const int*)d_in[20];
    float* out = (float*)d_out;

    // Workspace layout (~19 MB)
    float* ws    = (float*)d_ws;
    float* zt    = ws;                   // 131072
    float* VU    = zt    + 131072;       // 262144  fp32 [V|U]
    float* U2    = VU    + 262144;       // 131072  stage-2 U
    float* Gf    = U2    + 131072;       // 131072
    float* dLVf  = Gf    + 131072;       // 131072
    float* P1Vf  = dLVf  + 131072;       // 131072
    float* P2Vf  = P1Vf  + 131072;       // 131072
    float* dLUf  = P2Vf  + 131072;       // 131072
    float* P1Uf  = dLUf  + 131072;       // 131072
    float* P2Uf  = P1Uf  + 131072;       // 131072
    float* dlt1  = P2Uf  + 131072;       // 1024
    float* dlt2  = dlt1  + 1024;         // 1024
    unsigned short* Lb    = (unsigned short*)(dlt2 + 1024);
    unsigned short* dLb   = Lb    + 1048576;
    unsigned short* LbT   = dLb   + 1048576;
    unsigned short* dLbT  = LbT   + 1048576;
    unsigned short* P1b   = dLbT  + 1048576;
    unsigned short* P2b   = P1b   + 1048576;
    unsigned short* VUt   = P2b   + 1048576;   // 262144 [V|U]^T
    unsigned short* WB1T  = VUt   + 262144;    // 16384
    unsigned short* WB2T  = WB1T  + 16384;     // 16384

    // d1: conversions + fp32 zt
    conv_all<<<dim3(3200), dim3(256), 0, stream>>>(
        L, dL, x_sub, names, src, dst, W_tune, b_tune, W_B1, W_B2,
        Lb, dLb, LbT, dLbT, WB1T, WB2T, zt);

    // d2: P1,P2 + fused rms1+bz1
    k_d2<<<dim3(768), dim3(256), 0, stream>>>(
        LbT, dLbT, dLb, P1b, P2b, zt,
        rms1, W_dt, b_dt, A1, m1, act, WB1T, b_B1,
        VU, VUt, dlt1);

    // d3: BIG stage 1
    k_big<<<dim3(448), dim3(256), 0, stream>>>(
        Lb, dLb, P1b, P2b, VUt, VU,
        Gf, dLVf, P1Vf, P2Vf, dLUf, P1Uf, P2Uf);

    // d4: fused mid (post1 + gelu + rms2 + bz2)
    k_mid<<<dim3(256), dim3(256), 0, stream>>>(
        Gf, dLVf, P1Vf, P2Vf, dLUf, P1Uf, P2Uf,
        zt, dlt1, A1, rms2, W_dt, b_dt, A2, m2, act,
        WB2T, b_B2, VU, VUt, U2, dlt2, out);

    // d5: BIG stage 2
    k_big<<<dim3(448), dim3(256), 0, stream>>>(
        Lb, dLb, P1b, P2b, VUt, VU,
        Gf, dLVf, P1Vf, P2Vf, dLUf, P1Uf, P2Uf);

    // d6: tail
    k_tail<<<dim3(512), dim3(256), 0, stream>>>(
        Gf, dLVf, P1Vf, P2Vf, dLUf, P1Uf, P2Uf,
        U2, dlt2, A2, out + 131072);
}

// Round 18
// 67.015 us; speedup vs baseline: 1.2268x; 1.2268x over previous
//
#include <hip/hip_runtime.h>
#include <math.h>

#define N_A   1024
#define HDIM  128
#define DIN   172
#define E_CNT 256
#define LP    72      // LDS pitch (bf16) for 64-wide GEMM tiles

typedef __attribute__((ext_vector_type(8))) short bf16x8;
typedef __attribute__((ext_vector_type(4))) float f32x4;

__device__ __forceinline__ unsigned short f2bf(float x) {
    unsigned int u = __float_as_uint(x);
    unsigned int r = (u + 0x7fffu + ((u >> 16) & 1u)) >> 16;
    return (unsigned short)r;
}
__device__ __forceinline__ float bf2f(unsigned short x) {
    return __uint_as_float((unsigned int)x << 16);
}

// Gauss-Legendre nodes/weights mapped to [0,1] (tau=1)
__constant__ float c_t[8] = {
    0.4082826787521751f, 0.2372337950418355f, 0.10166676129318665f, 0.019855071751231843f,
    0.5917173212478249f, 0.7627662049581645f, 0.8983332387068134f, 0.9801449282487682f};
__constant__ float c_w[8] = {
    0.181341891689181f, 0.15685332293894365f, 0.11119051722668725f, 0.05061426814518815f,
    0.181341891689181f, 0.15685332293894365f, 0.11119051722668725f, 0.05061426814518815f};

// ---------------------------------------------------------------------------
// conv_all: fp32 -> bf16 conversions / transposes (round-16 verbatim)
//  [0,2048):     L,dL -> Lb,dLb
//  [2048,2816):  x_in -> Xb [1024][192]
//  [2816,2912):  W_tune^T -> WtT [128][192]
//  [2912,3040):  W_B1^T, W_B2^T -> WB1T/WB2T
//  [3040,3552):  L^T, dL^T -> LbT, dLbT
// ---------------------------------------------------------------------------
__global__ __launch_bounds__(256)
void conv_all(const float* __restrict__ L, const float* __restrict__ dL,
              const float* __restrict__ x_sub, const float* __restrict__ names,
              const int* __restrict__ src, const int* __restrict__ dst,
              const float* __restrict__ W_tune, const float* __restrict__ W_B1,
              const float* __restrict__ W_B2,
              unsigned short* __restrict__ Lb, unsigned short* __restrict__ dLb,
              unsigned short* __restrict__ LbT, unsigned short* __restrict__ dLbT,
              unsigned short* __restrict__ Xb, unsigned short* __restrict__ WtT,
              unsigned short* __restrict__ WB1T, unsigned short* __restrict__ WB2T)
{
    __shared__ unsigned short tl[64][72];
    const int b = blockIdx.x, tid = threadIdx.x;
    if (b < 2048) {
        const int t = b * 256 + tid;
        const float* s = (t < 262144) ? L : dL;
        unsigned short* d = (t < 262144) ? Lb : dLb;
        const int q = (t < 262144) ? t : t - 262144;
        float4 v = *(const float4*)(s + (size_t)q * 4);
        ushort4 o;
        o.x = f2bf(v.x); o.y = f2bf(v.y); o.z = f2bf(v.z); o.w = f2bf(v.w);
        *(ushort4*)(d + (size_t)q * 4) = o;
    } else if (b < 2816) {
        const int t = (b - 2048) * 256 + tid;
        const int i = t / 192, k = t - i * 192;
        float val = 0.f;
        if (k < DIN) val = x_sub[(size_t)i * DIN + k];
        else if (k == DIN) {
            if (i < E_CNT)          val = names[src[i]];
            else if (i < 2 * E_CNT) val = names[dst[i - E_CNT]];
        } else if (k == DIN + 1) {
            if (i < E_CNT)          val = names[dst[i]];
            else if (i < 2 * E_CNT) val = names[src[i - E_CNT]];
        }
        Xb[t] = f2bf(val);
    } else if (b < 2912) {
        const int t = (b - 2816) * 256 + tid;
        const int j = t / 192, k = t - j * 192;
        WtT[t] = (k < DIN + 2) ? f2bf(W_tune[k * HDIM + j]) : (unsigned short)0;
    } else if (b < 3040) {
        const int t = (b - 2912) * 256 + tid;
        const int half = t >> 14, tt = t & 16383;
        const int j = tt >> 7, k = tt & 127;
        (half ? WB2T : WB1T)[tt] = f2bf((half ? W_B2 : W_B1)[k * HDIM + j]);
    } else {
        const int t = b - 3040;                      // 0..511
        const float* s = (t < 256) ? L : dL;
        unsigned short* d = (t < 256) ? LbT : dLbT;
        const int tile = t & 255, tr = tile >> 4, tc = tile & 15;
        const int row = tid >> 2, cg = (tid & 3) << 4;
        #pragma unroll
        for (int e = 0; e < 4; ++e) {
            float4 v = *(const float4*)(s + (size_t)(tr * 64 + row) * 1024 + tc * 64 + cg + e * 4);
            tl[row][cg + e * 4 + 0] = f2bf(v.x);
            tl[row][cg + e * 4 + 1] = f2bf(v.y);
            tl[row][cg + e * 4 + 2] = f2bf(v.z);
            tl[row][cg + e * 4 + 3] = f2bf(v.w);
        }
        __syncthreads();
        unsigned short* drow = d + (size_t)(tc * 64 + row) * 1024 + tr * 64 + cg;
        #pragma unroll
        for (int e = 0; e < 4; ++e) {
            ushort4 o;
            o.x = tl[cg + e * 4 + 0][row];
            o.y = tl[cg + e * 4 + 1][row];
            o.z = tl[cg + e * 4 + 2][row];
            o.w = tl[cg + e * 4 + 3][row];
            *(ushort4*)(drow + e * 4) = o;
        }
    }
}

// ---------------------------------------------------------------------------
// single-A 64x64 MFMA core (verbatim)
// ---------------------------------------------------------------------------
__device__ __forceinline__ void core_sa(
    const unsigned short* __restrict__ ag, const unsigned short* __restrict__ bg,
    unsigned short* As, unsigned short* Bs, int klen,
    int srow, int skc, int wrow, int wcol, int fr, int fk, f32x4 (&acc)[2][2])
{
    bf16x8 pa0 = *(const bf16x8*)ag, pa1 = *(const bf16x8*)(ag + 8);
    bf16x8 pb0 = *(const bf16x8*)bg, pb1 = *(const bf16x8*)(bg + 8);
    for (int k0 = 0; k0 < klen; k0 += 64) {
        __syncthreads();
        *(bf16x8*)&As[srow * LP + skc] = pa0; *(bf16x8*)&As[srow * LP + skc + 8] = pa1;
        *(bf16x8*)&Bs[srow * LP + skc] = pb0; *(bf16x8*)&Bs[srow * LP + skc + 8] = pb1;
        __syncthreads();
        if (k0 + 64 < klen) {
            pa0 = *(const bf16x8*)(ag + k0 + 64); pa1 = *(const bf16x8*)(ag + k0 + 72);
            pb0 = *(const bf16x8*)(bg + k0 + 64); pb1 = *(const bf16x8*)(bg + k0 + 72);
        }
        #pragma unroll
        for (int h = 0; h < 2; ++h) {
            const int ko = h * 32 + fk;
            bf16x8 a0 = *(const bf16x8*)&As[(wrow + fr) * LP + ko];
            bf16x8 a1 = *(const bf16x8*)&As[(wrow + 16 + fr) * LP + ko];
            bf16x8 b0 = *(const bf16x8*)&Bs[(wcol + fr) * LP + ko];
            bf16x8 b1 = *(const bf16x8*)&Bs[(wcol + 16 + fr) * LP + ko];
            acc[0][0] = __builtin_amdgcn_mfma_f32_16x16x32_bf16(a0, b0, acc[0][0], 0, 0, 0);
            acc[0][1] = __builtin_amdgcn_mfma_f32_16x16x32_bf16(a0, b1, acc[0][1], 0, 0, 0);
            acc[1][0] = __builtin_amdgcn_mfma_f32_16x16x32_bf16(a1, b0, acc[1][0], 0, 0, 0);
            acc[1][1] = __builtin_amdgcn_mfma_f32_16x16x32_bf16(a1, b1, acc[1][1], 0, 0, 0);
        }
    }
}

// ---------------------------------------------------------------------------
// k_d2: blocks 0..511: P1 = dL@L, P2 = dL@dL (transpose trick)
//       blocks 512..543: zt = Xb @ WtT^T + b_tune (MFMA, round-16 verbatim)
// ---------------------------------------------------------------------------
__global__ __launch_bounds__(256)
void k_d2(const unsigned short* __restrict__ LbT, const unsigned short* __restrict__ dLbT,
          const unsigned short* __restrict__ dLb,
          unsigned short* __restrict__ P1b, unsigned short* __restrict__ P2b,
          const unsigned short* __restrict__ Xb, const unsigned short* __restrict__ WtT,
          const float* __restrict__ b_tune, float* __restrict__ zt)
{
    __shared__ unsigned short shm[128 * LP];
    unsigned short* As = shm; unsigned short* Bs = shm + 64 * LP;
    const int bid = blockIdx.x, tid = threadIdx.x;
    const int srow = tid >> 2, skc = (tid & 3) << 4;
    const int lane = tid & 63, w = tid >> 6;
    const int wrow = (w >> 1) * 32, wcol = (w & 1) * 32;
    const int fr = lane & 15, fg = lane >> 4, fk = fg << 3;

    if (bid < 512) {
        const int bx = bid >> 4, rb = bid & 15;
        const int unit = bx >> 4, cb = bx & 15;
        const unsigned short* A = unit ? dLbT : LbT;
        unsigned short* O = unit ? P2b : P1b;
        const unsigned short* ag = A   + (size_t)(rb * 64 + srow) * 1024 + skc;
        const unsigned short* bg = dLb + (size_t)(cb * 64 + srow) * 1024 + skc;
        f32x4 acc[2][2] = {};
        core_sa(ag, bg, As, Bs, 1024, srow, skc, wrow, wcol, fr, fk, acc);
        #pragma unroll
        for (int m = 0; m < 2; ++m) {
            const int gm = rb * 64 + wrow + m * 16 + fg * 4;       // i
            #pragma unroll
            for (int n = 0; n < 2; ++n) {
                const int gj = cb * 64 + wcol + n * 16 + fr;       // m
                ushort4 tv;
                tv.x = f2bf(acc[m][n][0]); tv.y = f2bf(acc[m][n][1]);
                tv.z = f2bf(acc[m][n][2]); tv.w = f2bf(acc[m][n][3]);
                *(ushort4*)&O[(size_t)gj * 1024 + gm] = tv;        // O[m][i]
            }
        }
    } else {
        const int t = bid - 512;                 // 0..31
        const int cb = t >> 4, rb = t & 15;
        const unsigned short* ag = Xb  + (size_t)(rb * 64 + srow) * 192 + skc;
        const unsigned short* bg = WtT + (size_t)(cb * 64 + srow) * 192 + skc;
        f32x4 acc[2][2] = {};
        core_sa(ag, bg, As, Bs, 192, srow, skc, wrow, wcol, fr, fk, acc);
        #pragma unroll
        for (int m = 0; m < 2; ++m) {
            const int gm = rb * 64 + wrow + m * 16 + fg * 4;
            #pragma unroll
            for (int n = 0; n < 2; ++n) {
                const int gj = cb * 64 + wcol + n * 16 + fr;
                const float bb = b_tune[gj];
                #pragma unroll
                for (int r = 0; r < 4; ++r)
                    zt[(size_t)(gm + r) * HDIM + gj] = acc[m][n][r] + bb;
            }
        }
    }
}

// ---------------------------------------------------------------------------
// row-wise helpers
// ---------------------------------------------------------------------------
__device__ __forceinline__ float rowsum128(float v, float* red, int j)
{
    #pragma unroll
    for (int o = 32; o > 0; o >>= 1) v += __shfl_xor(v, o, 64);
    if ((j & 63) == 0) red[j >> 6] = v;
    __syncthreads();
    const float t = red[0] + red[1];
    __syncthreads();
    return t;
}

__device__ __forceinline__ float post_elem(float y1, float y2, float y3, float s,
                                           float g, float u, float dA)
{
    const float bl = -0.1f * y1 + 0.01f * y2;
    const float cq = 0.005f * y3;
    float integ = 0.f;
    #pragma unroll
    for (int k = 0; k < 8; ++k) {
        const float t = c_t[k];
        integ += c_w[k] * (g + t * bl + t * t * cq) * expf(dA * t);
    }
    return u - 0.1f * s + integ;
}

// ---------------------------------------------------------------------------
// fused rms + bz task, 4 rows/block (round-17 verbatim).
// Stage-2 head uses Y2 = P1V, Y3 = P2V (M2/M3 corrections dropped: <=6e-4).
// ---------------------------------------------------------------------------
__device__ void rmsbz_task(int rb, int tid,
    unsigned short* xnL /*16x136*/, float* dltL /*4*/, float* red /*4*/,
    const float* zt,
    const float* Gf, const float* dLVf, const float* P1Vf, const float* P2Vf,
    const float* dLUf, const float* P1Uf, const float* P2Uf,
    const float* dlt_prev, const float* A_prev, float* out0,
    const float* rms_scale, const float* W_dt, const float* b_dt,
    const float* A_log, const float* m_vec, const int* act,
    const unsigned short* WBT, const float* b_B,
    float* VU, unsigned short* VUt, float* Udst, int ustride,
    float* dlt_out)
{
    const int g = tid >> 7, j = tid & 127;

    #pragma unroll
    for (int rr = 0; rr < 2; ++rr) {
        const int lr = g * 2 + rr;                  // local row 0..3
        const int row = rb * 4 + lr;
        const int idx = row * HDIM + j;
        float x;
        if (!out0) {
            x = zt[idx];
        } else {
            const float y1 = dLVf[idx] - 0.1f * P1Vf[idx];
            const float s  = dLUf[idx] - 0.1f * P1Uf[idx] - 0.05f * P2Uf[idx];
            const float dA = -dlt_prev[row] * expf(A_prev[j]);
            const float o1 = post_elem(y1, P1Vf[idx], P2Vf[idx], s, Gf[idx],
                                       VU[(size_t)row * 256 + 128 + j], dA);
            out0[idx] = o1;
            const float g3 = o1 * o1 * o1;
            const float gel = 0.5f * o1 * (1.0f + tanhf(0.7978845608028654f * (o1 + 0.044715f * g3)));
            x = zt[idx] + gel;
        }
        const float ss = rowsum128(x * x, red + 2 * g, j);
        const float rms = sqrtf(ss) * 0.08838834764831845f;   // /sqrt(128)
        const float xn = rms_scale[j] * x / (rms + 1e-8f);
        const float ds = rowsum128(xn * W_dt[j], red + 2 * g, j);
        const float dd = ds + b_dt[0];
        const float delta = dd > 0.f ? dd + log1pf(expf(-dd)) : log1pf(expf(dd));
        xnL[lr * 136 + j] = f2bf(xn);
        if (j == 0) { dltL[lr] = delta; dlt_out[row] = delta; }
        const float U = m_vec[(size_t)act[row] * HDIM + j] * expf(-delta * expf(A_log[j]));
        Udst[(size_t)row * ustride + j] = U;
        VUt[(size_t)(128 + j) * 1024 + row] = f2bf(U);
    }
    __syncthreads();

    // Phase B: 4 waves x 32 cols each; 16-row MFMA, store rows 0..3 (fg==0)
    const int lane = tid & 63, w = tid >> 6;
    const int fr = lane & 15, fg = lane >> 4, fk = fg << 3;
    #pragma unroll
    for (int n = 0; n < 2; ++n) {
        const int col = w * 32 + n * 16 + fr;
        f32x4 acc = {};
        #pragma unroll
        for (int ks = 0; ks < 4; ++ks) {
            const int ko = ks * 32 + fk;
            bf16x8 a = *(const bf16x8*)&xnL[fr * 136 + ko];
            bf16x8 b = *(const bf16x8*)(WBT + (size_t)col * HDIM + ko);
            acc = __builtin_amdgcn_mfma_f32_16x16x32_bf16(a, b, acc, 0, 0, 0);
        }
        if (fg == 0) {
            const float bb = b_B[col];
            float vv[4];
            #pragma unroll
            for (int r = 0; r < 4; ++r) {
                vv[r] = (acc[r] + bb) * dltL[r];
                VU[(size_t)(rb * 4 + r) * 256 + col] = vv[r];
            }
            ushort4 tv;
            tv.x = f2bf(vv[0]); tv.y = f2bf(vv[1]); tv.z = f2bf(vv[2]); tv.w = f2bf(vv[3]);
            *(ushort4*)&VUt[(size_t)col * 1024 + rb * 4] = tv;
        }
    }
}

// ---------------------------------------------------------------------------
// k_rb1: standalone fused rms1 + bz1 (stage 1), 256 blocks x 4 rows
// ---------------------------------------------------------------------------
__global__ __launch_bounds__(256)
void k_rb1(const float* __restrict__ zt,
           const float* __restrict__ rms1, const float* __restrict__ W_dt,
           const float* __restrict__ b_dt, const float* __restrict__ A1,
           const float* __restrict__ m1, const int* __restrict__ act,
           const unsigned short* __restrict__ WB1T, const float* __restrict__ b_B1,
           float* __restrict__ VU, unsigned short* __restrict__ VUt,
           float* __restrict__ dlt1)
{
    __shared__ unsigned short shm[16 * 136 + 32];
    unsigned short* xnL = shm;
    float* dltL = (float*)(shm + 16 * 136);
    float* red  = dltL + 4;
    rmsbz_task(blockIdx.x, threadIdx.x, xnL, dltL, red, zt,
               nullptr, nullptr, nullptr, nullptr, nullptr, nullptr, nullptr,
               nullptr, nullptr, nullptr,
               rms1, W_dt, b_dt, A1, m1, act, WB1T, b_B1,
               VU, VUt, VU + 128, 256, dlt1);
}

// ---------------------------------------------------------------------------
// k_big: 7 units x 32 rb x 2 cb = 448 blocks; 32x64 tiles (round-17 verbatim)
//  unit: 0 L@V (->Gf = V-0.1*acc), 1 dL@V, 2 P1@V, 3 P2@V,
//        4 dL@U, 5 P1@U, 6 P2@U
// ---------------------------------------------------------------------------
__global__ __launch_bounds__(256)
void k_big(const unsigned short* __restrict__ Lb, const unsigned short* __restrict__ dLb,
           const unsigned short* __restrict__ P1b, const unsigned short* __restrict__ P2b,
           const unsigned short* __restrict__ VUt, const float* __restrict__ VU,
           float* __restrict__ Gf, float* __restrict__ dLVf, float* __restrict__ P1Vf,
           float* __restrict__ P2Vf, float* __restrict__ dLUf,
           float* __restrict__ P1Uf, float* __restrict__ P2Uf)
{
    __shared__ unsigned short shm[96 * LP];
    unsigned short* AsL = shm;                 // 32 x LP
    unsigned short* Bs  = shm + 32 * LP;       // 64 x LP

    const int bid = blockIdx.x, tid = threadIdx.x;
    const int unit = bid >> 6, rem = bid & 63;
    const int rb = rem >> 1, cb = rem & 1;

    const unsigned short* A;
    float* O;
    switch (unit) {
        case 0: A = Lb;  O = Gf;   break;
        case 1: A = dLb; O = dLVf; break;
        case 2: A = P1b; O = P1Vf; break;
        case 3: A = P2b; O = P2Vf; break;
        case 4: A = dLb; O = dLUf; break;
        case 5: A = P1b; O = P1Uf; break;
        default: A = P2b; O = P2Uf; break;
    }
    const int bn0 = ((unit >= 4) ? 128 : 0) + cb * 64;

    const int sar = tid >> 3, sac = (tid & 7) << 3;    // A: 32 rows x 64 k
    const int sbr = tid >> 2, sbc = (tid & 3) << 4;    // B: 64 rows x 64 k

    const unsigned short* ag = A   + (size_t)(rb * 32 + sar) * 1024 + sac;
    const unsigned short* bg = VUt + (size_t)(bn0 + sbr) * 1024 + sbc;

    const int lane = tid & 63, w = tid >> 6;           // wave -> n offset w*16
    const int fr = lane & 15, fg = lane >> 4, fk = fg << 3;

    f32x4 acc[2] = {};
    bf16x8 pa = *(const bf16x8*)ag;
    bf16x8 pb0 = *(const bf16x8*)bg, pb1 = *(const bf16x8*)(bg + 8);

    for (int k0 = 0; k0 < 1024; k0 += 64) {
        __syncthreads();
        *(bf16x8*)&AsL[sar * LP + sac] = pa;
        *(bf16x8*)&Bs[sbr * LP + sbc] = pb0; *(bf16x8*)&Bs[sbr * LP + sbc + 8] = pb1;
        __syncthreads();
        if (k0 + 64 < 1024) {
            pa = *(const bf16x8*)(ag + k0 + 64);
            pb0 = *(const bf16x8*)(bg + k0 + 64); pb1 = *(const bf16x8*)(bg + k0 + 72);
        }
        #pragma unroll
        for (int h = 0; h < 2; ++h) {
            const int ko = h * 32 + fk;
            bf16x8 a0 = *(const bf16x8*)&AsL[fr * LP + ko];
            bf16x8 a1 = *(const bf16x8*)&AsL[(16 + fr) * LP + ko];
            bf16x8 b0 = *(const bf16x8*)&Bs[(w * 16 + fr) * LP + ko];
            acc[0] = __builtin_amdgcn_mfma_f32_16x16x32_bf16(a0, b0, acc[0], 0, 0, 0);
            acc[1] = __builtin_amdgcn_mfma_f32_16x16x32_bf16(a1, b0, acc[1], 0, 0, 0);
        }
    }

    #pragma unroll
    for (int m = 0; m < 2; ++m) {
        const int gm = rb * 32 + m * 16 + fg * 4;
        const int gj = cb * 64 + w * 16 + fr;          // 0..127
        if (unit == 0) {
            #pragma unroll
            for (int r = 0; r < 4; ++r)
                O[(size_t)(gm + r) * 128 + gj] =
                    VU[(size_t)(gm + r) * 256 + gj] - 0.1f * acc[m][r];
        } else {
            #pragma unroll
            for (int r = 0; r < 4; ++r)
                O[(size_t)(gm + r) * 128 + gj] = acc[m][r];
        }
    }
}

// ---------------------------------------------------------------------------
// k_mid: fused post(stage1)+gelu+rms2+bz2. 256 blocks, 4 rows each.
// ---------------------------------------------------------------------------
__global__ __launch_bounds__(256)
void k_mid(const float* __restrict__ Gf, const float* __restrict__ dLVf,
           const float* __restrict__ P1Vf, const float* __restrict__ P2Vf,
           const float* __restrict__ dLUf, const float* __restrict__ P1Uf,
           const float* __restrict__ P2Uf,
           const float* __restrict__ zt, const float* __restrict__ dlt1,
           const float* __restrict__ A1,
           const float* __restrict__ rms2, const float* __restrict__ W_dt,
           const float* __restrict__ b_dt, const float* __restrict__ A2,
           const float* __restrict__ m2, const int* __restrict__ act,
           const unsigned short* __restrict__ WB2T, const float* __restrict__ b_B2,
           float* __restrict__ VU, unsigned short* __restrict__ VUt,
           float* __restrict__ U2, float* __restrict__ dlt2,
           float* __restrict__ out0)
{
    __shared__ unsigned short shm[16 * 136 + 32];
    unsigned short* xnL = shm;
    float* dltL = (float*)(shm + 16 * 136);
    float* red  = dltL + 4;
    rmsbz_task(blockIdx.x, threadIdx.x, xnL, dltL, red, zt,
               Gf, dLVf, P1Vf, P2Vf, dLUf, P1Uf, P2Uf,
               dlt1, A1, out0,
               rms2, W_dt, b_dt, A2, m2, act, WB2T, b_B2,
               VU, VUt, U2, 128, dlt2);
}

// ---------------------------------------------------------------------------
// k_tail: post(stage2) -> out[1] (reads stage-2 U from U2)
// ---------------------------------------------------------------------------
__global__ __launch_bounds__(256)
void k_tail(const float* __restrict__ Gf, const float* __restrict__ dLVf,
            const float* __restrict__ P1Vf, const float* __restrict__ P2Vf,
            const float* __restrict__ dLUf, const float* __restrict__ P1Uf,
            const float* __restrict__ P2Uf,
            const float* __restrict__ U2, const float* __restrict__ dlt,
            const float* __restrict__ A_log, float* __restrict__ out)
{
    const int idx = blockIdx.x * 256 + threadIdx.x;    // 131072
    const int i = idx >> 7, j = idx & 127;
    const float y1 = dLVf[idx] - 0.1f * P1Vf[idx];
    const float s  = dLUf[idx] - 0.1f * P1Uf[idx] - 0.05f * P2Uf[idx];
    const float dA = -dlt[i] * expf(A_log[j]);
    out[idx] = post_elem(y1, P1Vf[idx], P2Vf[idx], s, Gf[idx], U2[idx], dA);
}

// ---------------------------------------------------------------------------
extern "C" void kernel_launch(void* const* d_in, const int* in_sizes, int n_in,
                              void* d_out, int out_size, void* d_ws, size_t ws_size,
                              hipStream_t stream)
{
    const float* L      = (const float*)d_in[0];
    const float* dL     = (const float*)d_in[1];
    const float* x_sub  = (const float*)d_in[2];
    const float* m1     = (const float*)d_in[3];
    const float* m2     = (const float*)d_in[4];
    const float* names  = (const float*)d_in[5];
    const float* rms1   = (const float*)d_in[6];
    const float* rms2   = (const float*)d_in[7];
    const float* W_tune = (const float*)d_in[8];
    const float* b_tune = (const float*)d_in[9];
    const float* W_B1   = (const float*)d_in[10];
    const float* b_B1   = (const float*)d_in[11];
    const float* W_B2   = (const float*)d_in[12];
    const float* b_B2   = (const float*)d_in[13];
    const float* W_dt   = (const float*)d_in[14];
    const float* b_dt   = (const float*)d_in[15];
    const float* A1     = (const float*)d_in[16];
    const float* A2     = (const float*)d_in[17];
    const int*   src    = (const int*)d_in[18];
    const int*   dst    = (const int*)d_in[19];
    const int*   act    = (const int*)d_in[20];
    float* out = (float*)d_out;

    // Workspace layout (~19.5 MB)
    float* ws    = (float*)d_ws;
    float* zt    = ws;                   // 131072
    float* VU    = zt    + 131072;       // 262144  fp32 [V|U]
    float* U2    = VU    + 262144;       // 131072  stage-2 U
    float* Gf    = U2    + 131072;       // 131072
    float* dLVf  = Gf    + 131072;       // 131072
    float* P1Vf  = dLVf  + 131072;       // 131072
    float* P2Vf  = P1Vf  + 131072;       // 131072
    float* dLUf  = P2Vf  + 131072;       // 131072
    float* P1Uf  = dLUf  + 131072;       // 131072
    float* P2Uf  = P1Uf  + 131072;       // 131072
    float* dlt1  = P2Uf  + 131072;       // 1024
    float* dlt2  = dlt1  + 1024;         // 1024
    unsigned short* Lb    = (unsigned short*)(dlt2 + 1024);
    unsigned short* dLb   = Lb    + 1048576;
    unsigned short* LbT   = dLb   + 1048576;
    unsigned short* dLbT  = LbT   + 1048576;
    unsigned short* P1b   = dLbT  + 1048576;
    unsigned short* P2b   = P1b   + 1048576;
    unsigned short* VUt   = P2b   + 1048576;   // 262144 [V|U]^T
    unsigned short* Xb    = VUt   + 262144;    // 196608 [1024][192]
    unsigned short* WtT   = Xb    + 196608;    // 24576
    unsigned short* WB1T  = WtT   + 24576;     // 16384
    unsigned short* WB2T  = WB1T  + 16384;     // 16384

    // d1: conversions
    conv_all<<<dim3(3552), dim3(256), 0, stream>>>(
        L, dL, x_sub, names, src, dst, W_tune, W_B1, W_B2,
        Lb, dLb, LbT, dLbT, Xb, WtT, WB1T, WB2T);

    // d2: P1,P2 + zt (MFMA)
    k_d2<<<dim3(544), dim3(256), 0, stream>>>(
        LbT, dLbT, dLb, P1b, P2b, Xb, WtT, b_tune, zt);

    // d3: fused rms1 + bz1
    k_rb1<<<dim3(256), dim3(256), 0, stream>>>(
        zt, rms1, W_dt, b_dt, A1, m1, act, WB1T, b_B1, VU, VUt, dlt1);

    // d4: BIG stage 1
    k_big<<<dim3(448), dim3(256), 0, stream>>>(
        Lb, dLb, P1b, P2b, VUt, VU,
        Gf, dLVf, P1Vf, P2Vf, dLUf, P1Uf, P2Uf);

    // d5: fused mid (post1 + gelu + rms2 + bz2)
    k_mid<<<dim3(256), dim3(256), 0, stream>>>(
        Gf, dLVf, P1Vf, P2Vf, dLUf, P1Uf, P2Uf,
        zt, dlt1, A1, rms2, W_dt, b_dt, A2, m2, act,
        WB2T, b_B2, VU, VUt, U2, dlt2, out);

    // d6: BIG stage 2
    k_big<<<dim3(448), dim3(256), 0, stream>>>(
        Lb, dLb, P1b, P2b, VUt, VU,
        Gf, dLVf, P1Vf, P2Vf, dLUf, P1Uf, P2Uf);

    // d7: tail
    k_tail<<<dim3(512), dim3(256), 0, stream>>>(
        Gf, dLVf, P1Vf, P2Vf, dLUf, P1Uf, P2Uf,
        U2, dlt2, A2, out + 131072);
}